// Round 10
// baseline (656.950 us; speedup 1.0000x reference)
//
#include <hip/hip_runtime.h>
#include <hip/hip_fp16.h>
#include <math.h>

// LSD (local shape descriptors), 128^3, 8 labels, sigma=5, truncate=3 -> 31-tap kernel.
//
// Algebra: for label mask m, define G_{abc} = (k_a *_z)(k_b *_y)(k_c *_x) m with
//   k0(u)=w(u), k1(u)=u w(u), k2(u)=u^2 w(u)  (w = normalized gaussian).
// At a voxel with mass=G000>0, p=G100/mass, q=G010/mass, s=G001/mass:
//   mean_offset = 0.5 - {p,q,s}/(2 sigma);  cov_ab = (G../mass - ..)/sigma^2.
// Translation-invariant: coords input not needed. Masks disjoint.
//
// R11: 2-deep pipes + ballot compaction, planar u16 Bu: 407 total
//      (pass_yx 289, conflicts 810K). MEASURED BEST structure.
// R12-R15: occupancy restructures all refuted (452/644/488/433).
// R16/R17: channel-interleaved b32 Bu: conflicts 13-15M regardless of list
//      order (sparse lanes -> random banks). Interleaved layout REFUTED for
//      sparse phase 2; planar u16 is the proven layout.
// R18 (this round): R11 base + instruction diet where it's provably real:
//   a) FULL UNROLL of both conv windows -> weight indices compile-time ->
//      kp/kq LDS tables deleted (was 408 ds_read/thread in phase 1 alone;
//      now cached scalar kernarg loads, ~free) and zero-padded boundary
//      taps fold away (~12% of phase-1 FMAs gone).
//   b) LDS 32.6 -> 31.6 KB (no kq4, LCAP 512->320): 5 blocks/CU (was 4).
//      LCAP 320 = mean+6.5sigma for uniform seg; dense fallback kept for
//      adversarial density.
//   c) f16 storage (A planes + Bu), planar layout. Everything else
//      R11-identical: register-pk ballot compaction, uint2 epilogue writes,
//      tile-major grid (1024,8), direct f32 stores, zero-designation
//      full-coverage (no memset).

constexpr int NV = 128 * 128 * 128;
constexpr int SLICE = 128 * 128;
constexpr int R = 15;
constexpr int KL = 31;
constexpr int CSTRIDE = 160;            // u16: 16 pad + 128 data + 16 pad
constexpr int RSTRIDE = 6 * CSTRIDE + 8; // 968 u16; row stagger
constexpr int LCAP = 320;

struct Kw { float k0[KL]; float k1[KL]; float k2[KL]; };

__device__ __forceinline__ void fma4(float4& a, float w, const float4& b) {
    a.x = fmaf(w, b.x, a.x); a.y = fmaf(w, b.y, a.y);
    a.z = fmaf(w, b.z, a.z); a.w = fmaf(w, b.w, a.w);
}

__device__ __forceinline__ float4 load_mask4(const unsigned char* p, int lab) {
    unsigned int u = *(const unsigned int*)p;
    return make_float4(((u       ) & 255u) == (unsigned)lab ? 1.f : 0.f,
                       ((u >>  8 ) & 255u) == (unsigned)lab ? 1.f : 0.f,
                       ((u >> 16 ) & 255u) == (unsigned)lab ? 1.f : 0.f,
                       ((u >> 24 ) & 255u) == (unsigned)lab ? 1.f : 0.f);
}
__device__ __forceinline__ float4 load_mask4(const int* p, int lab) {
    int4 s = *(const int4*)p;
    return make_float4(s.x == lab ? 1.f : 0.f, s.y == lab ? 1.f : 0.f,
                       s.z == lab ? 1.f : 0.f, s.w == lab ? 1.f : 0.f);
}

__device__ __forceinline__ unsigned seg_pack4(const unsigned char* p) {
    return *(const unsigned int*)p;
}
__device__ __forceinline__ unsigned seg_pack4(const int* p) {
    int4 v = *(const int4*)p;
    return (unsigned)(v.x & 255) | ((unsigned)(v.y & 255) << 8) |
           ((unsigned)(v.z & 255) << 16) | ((unsigned)(v.w & 255) << 24);
}

// ---- f16 helpers ----
__device__ __forceinline__ unsigned pack_h2(float a, float b) {
    __half2 h = __float22half2_rn(make_float2(a, b));
    return *reinterpret_cast<unsigned*>(&h);
}
__device__ __forceinline__ float hf_ld(const unsigned short* p) {
    return __half2float(__ushort_as_half(*p));
}
__device__ __forceinline__ float4 h4_to_f4(uint2 u) {
    return make_float4(__half2float(__ushort_as_half((unsigned short)(u.x & 0xffffu))),
                       __half2float(__ushort_as_half((unsigned short)(u.x >> 16))),
                       __half2float(__ushort_as_half((unsigned short)(u.y & 0xffffu))),
                       __half2float(__ushort_as_half((unsigned short)(u.y >> 16))));
}

// -------- pass_z: seg -> A[lab][3] f16 (z-conv). grid (512, nlab), 256 thr.
// Fully unrolled window: weight indices compile-time -> kernarg scalar loads,
// no LDS weight table, boundary taps elided.
template <typename ST>
__global__ __launch_bounds__(256) void pass_z_t(const ST* __restrict__ seg,
                                                unsigned short* __restrict__ A,
                                                int label0, size_t a_stride,
                                                Kw kw) {
    const int label = label0 + blockIdx.y;
    unsigned short* Ab = A + (size_t)blockIdx.y * a_stride;
    const int h = blockIdx.x, g = h & 7, l = h >> 3;       // 512 x-blocks
    const int tx = threadIdx.x & 31, ty = threadIdx.x >> 5;
    const int x0 = tx * 4;
    const int z0 = 16 * g + 4 * (l & 3);                   // XCD g owns z [16g,16g+16)
    const int y  = (l >> 2) * 8 + ty;

    float4 acc[4][3];
#pragma unroll
    for (int t = 0; t < 4; ++t)
#pragma unroll
        for (int c = 0; c < 3; ++c) acc[t][c] = make_float4(0.f, 0.f, 0.f, 0.f);

#pragma unroll
    for (int j = 0; j < 34; ++j) {                         // window: 4 outs + 30
        float4 m = make_float4(0.f, 0.f, 0.f, 0.f);
        int zz = z0 + j - R;                               // uniform per wave
        if ((unsigned)zz < 128u)
            m = load_mask4(seg + (zz * SLICE + y * 128 + x0), label);
#pragma unroll
        for (int t = 0; t < 4; ++t) {
            const int idx = j - t;                         // compile-time
            if (idx >= 0 && idx < KL) {
                fma4(acc[t][0], kw.k0[idx], m);
                fma4(acc[t][1], kw.k1[idx], m);
                fma4(acc[t][2], kw.k2[idx], m);
            }
        }
    }
#pragma unroll
    for (int t = 0; t < 4; ++t) {
        int base = (z0 + t) * SLICE + y * 128 + x0;
#pragma unroll
        for (int c = 0; c < 3; ++c) {
            float4 v = acc[t][c];
            uint2 pv = make_uint2(pack_h2(v.x, v.y), pack_h2(v.z, v.w));
            *reinterpret_cast<uint2*>(Ab + (size_t)c * NV + base) = pv;
        }
    }
}

// ---- per-voxel sparse x-conv (planar f16 Bu rows, zero-padded) ----
// value B_c(u) at u16 index rr*RSTRIDE + c*CSTRIDE + 16 + u; window tap j
// reads index x+1+j in [1,159) for x in [0,128). Pads are zero.
__device__ __forceinline__ void conv_voxel(const unsigned short* __restrict__ Bu,
                                           int rr, int x, const Kw& kw,
                                           float o[10]) {
    const unsigned short* row = Bu + rr * RSTRIDE + (x + 1);
    float g000 = 0, g001 = 0, g002 = 0, g010 = 0, g011 = 0,
          g020 = 0, g100 = 0, g101 = 0, g110 = 0, g200 = 0;
#pragma unroll
    for (int j = 0; j < KL; ++j) {
        float w0 = kw.k0[j], w1 = kw.k1[j], w2 = kw.k2[j];
        float b0 = hf_ld(row + 0 * CSTRIDE + j);
        float b1 = hf_ld(row + 1 * CSTRIDE + j);
        float b2 = hf_ld(row + 2 * CSTRIDE + j);
        float b3 = hf_ld(row + 3 * CSTRIDE + j);
        float b4 = hf_ld(row + 4 * CSTRIDE + j);
        float b5 = hf_ld(row + 5 * CSTRIDE + j);
        g000 = fmaf(w0, b0, g000); g001 = fmaf(w1, b0, g001); g002 = fmaf(w2, b0, g002);
        g010 = fmaf(w0, b1, g010); g011 = fmaf(w1, b1, g011);
        g020 = fmaf(w0, b2, g020);
        g100 = fmaf(w0, b3, g100); g101 = fmaf(w1, b3, g101);
        g110 = fmaf(w0, b4, g110);
        g200 = fmaf(w0, b5, g200);
    }
    float mass = g000;
    float denom = (mass > 0.f) ? mass : 1.f;
    float inv = 1.f / denom;
    float p = g100 * inv, q = g010 * inv, s = g001 * inv;
    const float cs = 1.0f / 25.0f;                         // 1/sigma^2
    o[0] = 0.5f - 0.1f * p;                                // 1/(2 sigma) = 0.1
    o[1] = 0.5f - 0.1f * q;
    o[2] = 0.5f - 0.1f * s;
    o[3] = (g200 * inv - p * p) * cs;
    o[4] = (g020 * inv - q * q) * cs;
    o[5] = (g002 * inv - s * s) * cs;
    o[6] = (g110 * inv - p * q) * cs;
    o[7] = (g011 * inv - q * s) * cs;
    o[8] = (g101 * inv - p * s) * cs;
    o[9] = mass;
#pragma unroll
    for (int c = 0; c < 10; ++c) o[c] = fminf(fmaxf(o[c], 0.f), 1.f);
}

__device__ __forceinline__ void do_voxel_out(const unsigned short* __restrict__ Bu,
                                             int rr, int x, int z0, int y0,
                                             float* __restrict__ out, const Kw& kw) {
    float o[10];
    conv_voxel(Bu, rr, x, kw, o);
    const int z2 = z0 + (rr >> 2), y2 = y0 + (rr & 3);
    const int v = (z2 * 128 + y2) * 128 + x;
#pragma unroll
    for (int c = 0; c < 10; ++c) out[(size_t)c * NV + v] = o[c];
}

__device__ __forceinline__ void zero_voxel(int rr, int x, int z0, int y0,
                                           float* __restrict__ out) {
    const int z2 = z0 + (rr >> 2), y2 = y0 + (rr & 3);
    const int v = (z2 * 128 + y2) * 128 + x;
#pragma unroll
    for (int c = 0; c < 10; ++c) out[(size_t)c * NV + v] = 0.f;
}

// -------- pass_yx: A[lab][3] f16 -> out. grid (1024, nlab), 128 thr. -------
// R11 geometry: 16-row tile (4z x 4y), T=4 sliding y-outs. Fully unrolled
// window (compile-time weights, no LDS table). Planar f16 Bu. Ballot
// compaction from preloaded pk registers. Phase 2: sparse conv + direct f32
// stores; zero-designated non-label voxels give full coverage (no memset).
template <typename ST>
__global__ __launch_bounds__(128) void pass_yx(const unsigned short* __restrict__ A,
                                               const ST* __restrict__ seg,
                                               float* __restrict__ out,
                                               int label0, size_t a_stride,
                                               Kw kw) {
    __shared__ __align__(16) unsigned short Bu[16 * RSTRIDE];  // 30,976 B
    __shared__ unsigned short lst[LCAP];                       // 640 B
    __shared__ int cnt;

    // zero Bu (pads must be exactly 0) + counter
    {
        uint4 z4 = make_uint4(0, 0, 0, 0);
        uint4* b4 = (uint4*)Bu;                            // 16*968*2/16 = 1936
        for (int i = threadIdx.x; i < 1936; i += 128) b4[i] = z4;
    }
    if (threadIdx.x == 0) cnt = 0;
    __syncthreads();

    const int labi = blockIdx.y;
    const int label = label0 + labi;
    const unsigned short* Ab = A + (size_t)labi * a_stride;
    const int h = blockIdx.x, g = h & 7, l = h >> 3;       // 1024 x-blocks
    const int tx = threadIdx.x & 31, tz = threadIdx.x >> 5; // tz 0..3
    const int x0 = tx * 4;
    const int z0 = 16 * g + 4 * (l & 3);                   // XCD g owns z slab
    const int y0 = (l >> 2) * 4;                           // 32 y-tiles
    const int zs = (z0 + tz) * SLICE;

    // pre-issue compaction seg loads (complete under phase 1)
    const int rr_c = threadIdx.x >> 3, q0_c = threadIdx.x & 7;
    const int vrow_c = ((z0 + (rr_c >> 2)) * 128 + (y0 + (rr_c & 3))) * 128;
    unsigned pk[4];
#pragma unroll
    for (int k = 0; k < 4; ++k)
        pk[k] = seg_pack4(seg + vrow_c + 4 * (q0_c + 8 * k));

    // ---- phase 1: y-conv, T=4 outputs, fully unrolled window ----
    float4 acc[6][4];                                      // [ch][t]
#pragma unroll
    for (int c = 0; c < 6; ++c)
#pragma unroll
        for (int t = 0; t < 4; ++t) acc[c][t] = make_float4(0.f, 0.f, 0.f, 0.f);

#pragma unroll
    for (int j = 0; j < 34; ++j) {
        uint2 u0 = make_uint2(0u, 0u), u1 = u0, u2 = u0;
        int yy = y0 + j - R;                               // uniform per block
        if ((unsigned)yy < 128u) {
            int base = zs + yy * 128 + x0;
            u0 = *(const uint2*)(Ab + base);
            u1 = *(const uint2*)(Ab + NV + base);
            u2 = *(const uint2*)(Ab + 2 * NV + base);
        }
        float4 a0 = h4_to_f4(u0), a1 = h4_to_f4(u1), a2 = h4_to_f4(u2);
#pragma unroll
        for (int t = 0; t < 4; ++t) {
            const int idx = j - t;                         // compile-time
            if (idx >= 0 && idx < KL) {
                float w0 = kw.k0[idx], w1 = kw.k1[idx], w2 = kw.k2[idx];
                fma4(acc[0][t], w0, a0);
                fma4(acc[1][t], w1, a0);
                fma4(acc[2][t], w2, a0);
                fma4(acc[3][t], w0, a1);
                fma4(acc[4][t], w1, a1);
                fma4(acc[5][t], w0, a2);
            }
        }
    }

    // ---- epilogue: write planar Bu rows (uint2 per (t,c)) ----
#pragma unroll
    for (int t = 0; t < 4; ++t) {
        const int row = tz * 4 + t;                        // row = 4*zsub + ysub
#pragma unroll
        for (int c = 0; c < 6; ++c) {
            uint2 pv = make_uint2(pack_h2(acc[c][t].x, acc[c][t].y),
                                  pack_h2(acc[c][t].z, acc[c][t].w));
            *reinterpret_cast<uint2*>(Bu + row * RSTRIDE + c * CSTRIDE + 16 + x0) = pv;
        }
    }

    // ---- compaction: ballot-based, 1 atomic per wave per step ----
    {
        const int lane = threadIdx.x & 63;
        const unsigned long long below_mask = (1ull << lane) - 1ull;
#pragma unroll
        for (int k = 0; k < 4; ++k) {
            const unsigned w = pk[k];
#pragma unroll
            for (int t = 0; t < 4; ++t) {
                const int sv = (int)((w >> (8 * t)) & 255u);
                const int x = 4 * (q0_c + 8 * k) + t;
                const bool mt = (sv == label);
                const bool zt = !mt && (sv < 1 || sv > 8) &&
                                (((x & 7) + 1) == label);
                const bool pred = mt | zt;
                unsigned long long bal = __ballot(pred);
                int base = 0;
                if (lane == 0 && bal) base = atomicAdd(&cnt, (int)__popcll(bal));
                base = __shfl(base, 0);
                if (pred) {
                    int pos = base + (int)__popcll(bal & below_mask);
                    if (pos < LCAP)
                        lst[pos] = (unsigned short)((rr_c << 7) | x | (zt ? 0x8000 : 0));
                }
            }
        }
    }

    __syncthreads();

    // ---- phase 2: sparse x-conv + epilogue (or zero-store) ----
    const int total = cnt;
    if (total <= LCAP) {
        for (int e = threadIdx.x; e < total; e += 128) {
            int ent = lst[e];
            int rr = (ent >> 7) & 15, x = ent & 127;
            if (ent & 0x8000) zero_voxel(rr, x, z0, y0, out);
            else do_voxel_out(Bu, rr, x, z0, y0, out, kw);
        }
    } else {
        // adversarial-density fallback: dense masked sweep (same math)
        for (int e = threadIdx.x; e < 2048; e += 128) {
            int rr = e >> 7, x = e & 127;
            int z2 = z0 + (rr >> 2), y2 = y0 + (rr & 3);
            int sv = (int)seg[(z2 * 128 + y2) * 128 + x] & 255;
            if (sv == label)
                do_voxel_out(Bu, rr, x, z0, y0, out, kw);
            else if ((sv < 1 || sv > 8) && (((x & 7) + 1) == label))
                zero_voxel(rr, x, z0, y0, out);
        }
    }
}

__global__ __launch_bounds__(256) void seg_to_u8(const int* __restrict__ seg,
                                                 unsigned char* __restrict__ seg8) {
    const int t = blockIdx.x * 256 + threadIdx.x;          // 2048 blocks
    const int4 s = ((const int4*)seg)[t];
    ((uchar4*)seg8)[t] = make_uchar4((unsigned char)s.x, (unsigned char)s.y,
                                     (unsigned char)s.z, (unsigned char)s.w);
}

extern "C" void kernel_launch(void* const* d_in, const int* in_sizes, int n_in,
                              void* d_out, int out_size, void* d_ws, size_t ws_size,
                              hipStream_t stream) {
    const int* seg = (const int*)d_in[0];
    // d_in[1] (coords) unused: math is translation-invariant.
    float* out = (float*)d_out;
    unsigned short* A = (unsigned short*)d_ws;             // f16 A planes
    const size_t AVOL = (size_t)3 * NV;                    // u16 elements/label

    Kw kw;
    double gg[KL], S = 0.0;
    for (int j = 0; j < KL; ++j) { double d = j - R; gg[j] = exp(-0.5 * d * d / 25.0); S += gg[j]; }
    for (int j = 0; j < KL; ++j) {
        double gn = gg[j] / S, d = j - R;
        kw.k0[j] = (float)gn;
        kw.k1[j] = (float)(-d * gn);   // conv kernel k1 evaluated at (Z - t) = -d
        kw.k2[j] = (float)(d * d * gn);
    }

    // No memset: every output voxel is written exactly once across labels.

    const size_t need_all = 8 * AVOL * sizeof(unsigned short) + NV;  // A_all + seg8
    const size_t need_one = AVOL * sizeof(unsigned short) + NV;

    if (ws_size >= need_all) {
        // 3-dispatch path: labels batched in blockIdx.y, tile-major in x.
        unsigned char* seg8 = (unsigned char*)d_ws + 8 * AVOL * sizeof(unsigned short);
        seg_to_u8<<<dim3(2048), dim3(256), 0, stream>>>(seg, seg8);
        pass_z_t<unsigned char><<<dim3(512, 8), dim3(256), 0, stream>>>(
            seg8, A, 1, AVOL, kw);
        pass_yx<unsigned char><<<dim3(1024, 8), dim3(128), 0, stream>>>(
            A, seg8, out, 1, AVOL, kw);
    } else if (ws_size >= need_one) {
        unsigned char* seg8 = (unsigned char*)d_ws + AVOL * sizeof(unsigned short);
        seg_to_u8<<<dim3(2048), dim3(256), 0, stream>>>(seg, seg8);
        for (int label = 1; label <= 8; ++label) {
            pass_z_t<unsigned char><<<dim3(512, 1), dim3(256), 0, stream>>>(
                seg8, A, label, 0, kw);
            pass_yx<unsigned char><<<dim3(1024, 1), dim3(128), 0, stream>>>(
                A, seg8, out, label, 0, kw);
        }
    } else {
        for (int label = 1; label <= 8; ++label) {
            pass_z_t<int><<<dim3(512, 1), dim3(256), 0, stream>>>(
                seg, A, label, 0, kw);
            pass_yx<int><<<dim3(1024, 1), dim3(128), 0, stream>>>(
                A, seg, out, label, 0, kw);
        }
    }
}

// Round 11
// 422.828 us; speedup vs baseline: 1.5537x; 1.5537x over previous
//
#include <hip/hip_runtime.h>
#include <hip/hip_fp16.h>
#include <math.h>

// LSD (local shape descriptors), 128^3, 8 labels, sigma=5, truncate=3 -> 31-tap kernel.
//
// Algebra: for label mask m, define G_{abc} = (k_a *_z)(k_b *_y)(k_c *_x) m with
//   k0(u)=w(u), k1(u)=u w(u), k2(u)=u^2 w(u)  (w = normalized gaussian).
// At a voxel with mass=G000>0, p=G100/mass, q=G010/mass, s=G001/mass:
//   mean_offset = 0.5 - {p,q,s}/(2 sigma);  cov_ab = (G../mass - ..)/sigma^2.
// Translation-invariant: coords input not needed. Masks disjoint.
//
// Measured record (totals; pass_yx in parens):
//   R11 407 (289)  R12 452 (333)  R13 644 (519, spills)  R14 488 (380)
//   R15 433 (313)  R16 409 (313, 15M conflicts)  R17 405 (302)
//   R18 657 (517, VGPR 256 spills -- full unroll REFUTED)
// Proven-good: R11 geometry (grid 1024x8, 16-row tile, T=4), rolled 2-deep
//   pipeline, register-pk ballot compaction, PLANAR u16 Bu (810K conflicts),
//   kq4 float4 weight table (4 b128/iter), direct f32 stores, no memset.
// Proven-bad: interleaved Bu, full unroll, launch-bounds forcing, wave-role
//   splits, f16 LDS out-staging, occupancy restructures.
// R19 (this round): consolidation + the one untested clean lever:
//   LDS <= 32 KB on the R11 structure -> 5 blocks/CU (was 4).
//   Bu 30,976 (planar f16) + kq4 640 + lst 704 (LCAP 352) + 4 = 32,324 B.
//   VGPR ~80-90 caps waves at 16/CU, so LDS was the binding limit; this
//   buys +25% TLP with zero structural change.

constexpr int NV = 128 * 128 * 128;
constexpr int SLICE = 128 * 128;
constexpr int R = 15;
constexpr int KL = 31;
constexpr int CSTRIDE = 160;            // u16: 16 pad + 128 data + 16 pad
constexpr int RSTRIDE = 6 * CSTRIDE + 8; // 968 u16; row stagger
constexpr int LCAP = 352;               // mean 256 + 6.4 sigma (uniform seg)

struct Kw { float k0[KL]; float k1[KL]; float k2[KL]; };

__device__ __forceinline__ void fma4(float4& a, float w, const float4& b) {
    a.x = fmaf(w, b.x, a.x); a.y = fmaf(w, b.y, a.y);
    a.z = fmaf(w, b.z, a.z); a.w = fmaf(w, b.w, a.w);
}

__device__ __forceinline__ float4 load_mask4(const unsigned char* p, int lab) {
    unsigned int u = *(const unsigned int*)p;
    return make_float4(((u       ) & 255u) == (unsigned)lab ? 1.f : 0.f,
                       ((u >>  8 ) & 255u) == (unsigned)lab ? 1.f : 0.f,
                       ((u >> 16 ) & 255u) == (unsigned)lab ? 1.f : 0.f,
                       ((u >> 24 ) & 255u) == (unsigned)lab ? 1.f : 0.f);
}
__device__ __forceinline__ float4 load_mask4(const int* p, int lab) {
    int4 s = *(const int4*)p;
    return make_float4(s.x == lab ? 1.f : 0.f, s.y == lab ? 1.f : 0.f,
                       s.z == lab ? 1.f : 0.f, s.w == lab ? 1.f : 0.f);
}

__device__ __forceinline__ unsigned seg_pack4(const unsigned char* p) {
    return *(const unsigned int*)p;
}
__device__ __forceinline__ unsigned seg_pack4(const int* p) {
    int4 v = *(const int4*)p;
    return (unsigned)(v.x & 255) | ((unsigned)(v.y & 255) << 8) |
           ((unsigned)(v.z & 255) << 16) | ((unsigned)(v.w & 255) << 24);
}

// ---- f16 helpers ----
__device__ __forceinline__ unsigned pack_h2(float a, float b) {
    __half2 h = __float22half2_rn(make_float2(a, b));
    return *reinterpret_cast<unsigned*>(&h);
}
__device__ __forceinline__ float hf_ld(const unsigned short* p) {
    return __half2float(__ushort_as_half(*p));
}
__device__ __forceinline__ float4 h4_to_f4(uint2 u) {
    return make_float4(__half2float(__ushort_as_half((unsigned short)(u.x & 0xffffu))),
                       __half2float(__ushort_as_half((unsigned short)(u.x >> 16))),
                       __half2float(__ushort_as_half((unsigned short)(u.y & 0xffffu))),
                       __half2float(__ushort_as_half((unsigned short)(u.y >> 16))));
}

// -------- pass_z: seg -> A[lab][3] f16 (z-conv). grid (512, nlab), 256 thr.
// Rolled 2-deep pipelined window + LDS weight table (proven loop shape).
template <typename ST>
__global__ __launch_bounds__(256) void pass_z_t(const ST* __restrict__ seg,
                                                unsigned short* __restrict__ A,
                                                int label0, size_t a_stride,
                                                Kw kw) {
    __shared__ float kp[3][37];           // zero-padded: kp[c][i] = k_c[i-3]
    if (threadIdx.x < 37) {
        int i = threadIdx.x, j = i - 3; bool ok = (j >= 0) && (j < KL);
        kp[0][i] = ok ? kw.k0[j] : 0.f;
        kp[1][i] = ok ? kw.k1[j] : 0.f;
        kp[2][i] = ok ? kw.k2[j] : 0.f;
    }
    __syncthreads();
    const int label = label0 + blockIdx.y;
    unsigned short* Ab = A + (size_t)blockIdx.y * a_stride;
    const int h = blockIdx.x, g = h & 7, l = h >> 3;       // 512 x-blocks
    const int tx = threadIdx.x & 31, ty = threadIdx.x >> 5;
    const int x0 = tx * 4;
    const int z0 = 16 * g + 4 * (l & 3);                   // XCD g owns z [16g,16g+16)
    const int y  = (l >> 2) * 8 + ty;

    float4 acc[4][3];
#pragma unroll
    for (int t = 0; t < 4; ++t)
#pragma unroll
        for (int c = 0; c < 3; ++c) acc[t][c] = make_float4(0.f, 0.f, 0.f, 0.f);

    // 2-deep pipelined sliding window: load j+2 while FMAing j.
    float4 cm = make_float4(0.f, 0.f, 0.f, 0.f), nm = cm;
    {
        int zz = z0 - R;
        if ((unsigned)zz < 128u)
            cm = load_mask4(seg + (zz * SLICE + y * 128 + x0), label);
        int zn = z0 + 1 - R;
        if ((unsigned)zn < 128u)
            nm = load_mask4(seg + (zn * SLICE + y * 128 + x0), label);
    }
    for (int j = 0; j < 34; ++j) {                         // window: 4 outs + 30
        float4 fm = make_float4(0.f, 0.f, 0.f, 0.f);
        int zz = z0 + j + 2 - R;                           // uniform per wave
        if (j < 32 && (unsigned)zz < 128u)
            fm = load_mask4(seg + (zz * SLICE + y * 128 + x0), label);
#pragma unroll
        for (int t = 0; t < 4; ++t) {
            int i = j - t + 3;                             // padded weight index
            fma4(acc[t][0], kp[0][i], cm);
            fma4(acc[t][1], kp[1][i], cm);
            fma4(acc[t][2], kp[2][i], cm);
        }
        cm = nm; nm = fm;
    }
#pragma unroll
    for (int t = 0; t < 4; ++t) {
        int base = (z0 + t) * SLICE + y * 128 + x0;
#pragma unroll
        for (int c = 0; c < 3; ++c) {
            float4 v = acc[t][c];
            uint2 pv = make_uint2(pack_h2(v.x, v.y), pack_h2(v.z, v.w));
            *reinterpret_cast<uint2*>(Ab + (size_t)c * NV + base) = pv;
        }
    }
}

// ---- per-voxel sparse x-conv (planar f16 Bu rows, zero-padded) ----
// value B_c(u) at u16 index rr*RSTRIDE + c*CSTRIDE + 16 + u; window tap j
// reads index x+1+j in [1,159) for x in [0,128). Pads are zero.
__device__ __forceinline__ void conv_voxel(const unsigned short* __restrict__ Bu,
                                           int rr, int x, const Kw& kw,
                                           float o[10]) {
    const unsigned short* row = Bu + rr * RSTRIDE + (x + 1);
    float g000 = 0, g001 = 0, g002 = 0, g010 = 0, g011 = 0,
          g020 = 0, g100 = 0, g101 = 0, g110 = 0, g200 = 0;
#pragma unroll
    for (int j = 0; j < KL; ++j) {
        float w0 = kw.k0[j], w1 = kw.k1[j], w2 = kw.k2[j];
        float b0 = hf_ld(row + 0 * CSTRIDE + j);
        float b1 = hf_ld(row + 1 * CSTRIDE + j);
        float b2 = hf_ld(row + 2 * CSTRIDE + j);
        float b3 = hf_ld(row + 3 * CSTRIDE + j);
        float b4 = hf_ld(row + 4 * CSTRIDE + j);
        float b5 = hf_ld(row + 5 * CSTRIDE + j);
        g000 = fmaf(w0, b0, g000); g001 = fmaf(w1, b0, g001); g002 = fmaf(w2, b0, g002);
        g010 = fmaf(w0, b1, g010); g011 = fmaf(w1, b1, g011);
        g020 = fmaf(w0, b2, g020);
        g100 = fmaf(w0, b3, g100); g101 = fmaf(w1, b3, g101);
        g110 = fmaf(w0, b4, g110);
        g200 = fmaf(w0, b5, g200);
    }
    float mass = g000;
    float denom = (mass > 0.f) ? mass : 1.f;
    float inv = 1.f / denom;
    float p = g100 * inv, q = g010 * inv, s = g001 * inv;
    const float cs = 1.0f / 25.0f;                         // 1/sigma^2
    o[0] = 0.5f - 0.1f * p;                                // 1/(2 sigma) = 0.1
    o[1] = 0.5f - 0.1f * q;
    o[2] = 0.5f - 0.1f * s;
    o[3] = (g200 * inv - p * p) * cs;
    o[4] = (g020 * inv - q * q) * cs;
    o[5] = (g002 * inv - s * s) * cs;
    o[6] = (g110 * inv - p * q) * cs;
    o[7] = (g011 * inv - q * s) * cs;
    o[8] = (g101 * inv - p * s) * cs;
    o[9] = mass;
#pragma unroll
    for (int c = 0; c < 10; ++c) o[c] = fminf(fmaxf(o[c], 0.f), 1.f);
}

__device__ __forceinline__ void do_voxel_out(const unsigned short* __restrict__ Bu,
                                             int rr, int x, int z0, int y0,
                                             float* __restrict__ out, const Kw& kw) {
    float o[10];
    conv_voxel(Bu, rr, x, kw, o);
    const int z2 = z0 + (rr >> 2), y2 = y0 + (rr & 3);
    const int v = (z2 * 128 + y2) * 128 + x;
#pragma unroll
    for (int c = 0; c < 10; ++c) out[(size_t)c * NV + v] = o[c];
}

__device__ __forceinline__ void zero_voxel(int rr, int x, int z0, int y0,
                                           float* __restrict__ out) {
    const int z2 = z0 + (rr >> 2), y2 = y0 + (rr & 3);
    const int v = (z2 * 128 + y2) * 128 + x;
#pragma unroll
    for (int c = 0; c < 10; ++c) out[(size_t)c * NV + v] = 0.f;
}

// -------- pass_yx: A[lab][3] f16 -> out. grid (1024, nlab), 128 thr. -------
// R11 geometry: 16-row tile (4z x 4y), T=4 sliding y-outs, 2-deep pipeline.
// kq4 float4 weight table: 1 ds_read_b128 per (j,t) serves w0,w1,w2 (4/iter
// instead of 12). Planar f16 Bu. Register-pk ballot compaction. Phase 2:
// sparse conv + direct f32 stores; zero-designated non-label voxels give
// full coverage (no memset). LDS 32,324 B -> 5 blocks/CU.
template <typename ST>
__global__ __launch_bounds__(128) void pass_yx(const unsigned short* __restrict__ A,
                                               const ST* __restrict__ seg,
                                               float* __restrict__ out,
                                               int label0, size_t a_stride,
                                               Kw kw) {
    __shared__ float4 kq4[40];                                 // {k0,k1,k2,0}[i-3]
    __shared__ __align__(16) unsigned short Bu[16 * RSTRIDE];  // 30,976 B
    __shared__ unsigned short lst[LCAP];                       // 704 B
    __shared__ int cnt;

    // zero Bu (pads must be exactly 0) + weights + counter
    {
        uint4 z4 = make_uint4(0, 0, 0, 0);
        uint4* b4 = (uint4*)Bu;                            // 16*968*2/16 = 1936
        for (int i = threadIdx.x; i < 1936; i += 128) b4[i] = z4;
    }
    if (threadIdx.x < 40) {
        int i = threadIdx.x, j = i - 3; bool ok = (j >= 0) && (j < KL);
        kq4[i] = make_float4(ok ? kw.k0[j] : 0.f, ok ? kw.k1[j] : 0.f,
                             ok ? kw.k2[j] : 0.f, 0.f);
    }
    if (threadIdx.x == 0) cnt = 0;
    __syncthreads();

    const int labi = blockIdx.y;
    const int label = label0 + labi;
    const unsigned short* Ab = A + (size_t)labi * a_stride;
    const int h = blockIdx.x, g = h & 7, l = h >> 3;       // 1024 x-blocks
    const int tx = threadIdx.x & 31, tz = threadIdx.x >> 5; // tz 0..3
    const int x0 = tx * 4;
    const int z0 = 16 * g + 4 * (l & 3);                   // XCD g owns z slab
    const int y0 = (l >> 2) * 4;                           // 32 y-tiles
    const int zs = (z0 + tz) * SLICE;

    // pre-issue compaction seg loads (complete under phase 1)
    const int rr_c = threadIdx.x >> 3, q0_c = threadIdx.x & 7;
    const int vrow_c = ((z0 + (rr_c >> 2)) * 128 + (y0 + (rr_c & 3))) * 128;
    unsigned pk[4];
#pragma unroll
    for (int k = 0; k < 4; ++k)
        pk[k] = seg_pack4(seg + vrow_c + 4 * (q0_c + 8 * k));

    // ---- phase 1: y-conv, T=4 outputs sliding in registers, 2-deep pipe ----
    float4 acc[6][4];                                      // [ch][t]
#pragma unroll
    for (int c = 0; c < 6; ++c)
#pragma unroll
        for (int t = 0; t < 4; ++t) acc[c][t] = make_float4(0.f, 0.f, 0.f, 0.f);

    uint2 c0 = make_uint2(0u, 0u), c1 = c0, c2 = c0;       // packed f16 x4
    uint2 n0 = c0, n1 = c0, n2 = c0;
    {
        int yy = y0 - R;
        if ((unsigned)yy < 128u) {
            int base = zs + yy * 128 + x0;
            c0 = *(const uint2*)(Ab + base);
            c1 = *(const uint2*)(Ab + NV + base);
            c2 = *(const uint2*)(Ab + 2 * NV + base);
        }
        int yn = y0 + 1 - R;
        if ((unsigned)yn < 128u) {
            int base = zs + yn * 128 + x0;
            n0 = *(const uint2*)(Ab + base);
            n1 = *(const uint2*)(Ab + NV + base);
            n2 = *(const uint2*)(Ab + 2 * NV + base);
        }
    }
    for (int j = 0; j < 34; ++j) {
        uint2 f0 = make_uint2(0u, 0u), f1 = f0, f2 = f0;
        int yy = y0 + j + 2 - R;
        if (j < 32 && (unsigned)yy < 128u) {
            int base = zs + yy * 128 + x0;
            f0 = *(const uint2*)(Ab + base);
            f1 = *(const uint2*)(Ab + NV + base);
            f2 = *(const uint2*)(Ab + 2 * NV + base);
        }
        float4 a0 = h4_to_f4(c0), a1 = h4_to_f4(c1), a2 = h4_to_f4(c2);
#pragma unroll
        for (int t = 0; t < 4; ++t) {
            float4 wv = kq4[j + 3 - t];
            fma4(acc[0][t], wv.x, a0);
            fma4(acc[1][t], wv.y, a0);
            fma4(acc[2][t], wv.z, a0);
            fma4(acc[3][t], wv.x, a1);
            fma4(acc[4][t], wv.y, a1);
            fma4(acc[5][t], wv.x, a2);
        }
        c0 = n0; c1 = n1; c2 = n2;
        n0 = f0; n1 = f1; n2 = f2;
    }

    // ---- epilogue: write planar Bu rows (uint2 per (t,c)) ----
#pragma unroll
    for (int t = 0; t < 4; ++t) {
        const int row = tz * 4 + t;                        // row = 4*zsub + ysub
#pragma unroll
        for (int c = 0; c < 6; ++c) {
            uint2 pv = make_uint2(pack_h2(acc[c][t].x, acc[c][t].y),
                                  pack_h2(acc[c][t].z, acc[c][t].w));
            *reinterpret_cast<uint2*>(Bu + row * RSTRIDE + c * CSTRIDE + 16 + x0) = pv;
        }
    }

    // ---- compaction: ballot-based, 1 atomic per wave per step ----
    {
        const int lane = threadIdx.x & 63;
        const unsigned long long below_mask = (1ull << lane) - 1ull;
#pragma unroll
        for (int k = 0; k < 4; ++k) {
            const unsigned w = pk[k];
#pragma unroll
            for (int t = 0; t < 4; ++t) {
                const int sv = (int)((w >> (8 * t)) & 255u);
                const int x = 4 * (q0_c + 8 * k) + t;
                const bool mt = (sv == label);
                const bool zt = !mt && (sv < 1 || sv > 8) &&
                                (((x & 7) + 1) == label);
                const bool pred = mt | zt;
                unsigned long long bal = __ballot(pred);
                int base = 0;
                if (lane == 0 && bal) base = atomicAdd(&cnt, (int)__popcll(bal));
                base = __shfl(base, 0);
                if (pred) {
                    int pos = base + (int)__popcll(bal & below_mask);
                    if (pos < LCAP)
                        lst[pos] = (unsigned short)((rr_c << 7) | x | (zt ? 0x8000 : 0));
                }
            }
        }
    }

    __syncthreads();

    // ---- phase 2: sparse x-conv + epilogue (or zero-store) ----
    const int total = cnt;
    if (total <= LCAP) {
        for (int e = threadIdx.x; e < total; e += 128) {
            int ent = lst[e];
            int rr = (ent >> 7) & 15, x = ent & 127;
            if (ent & 0x8000) zero_voxel(rr, x, z0, y0, out);
            else do_voxel_out(Bu, rr, x, z0, y0, out, kw);
        }
    } else {
        // adversarial-density fallback: dense masked sweep (same math)
        for (int e = threadIdx.x; e < 2048; e += 128) {
            int rr = e >> 7, x = e & 127;
            int z2 = z0 + (rr >> 2), y2 = y0 + (rr & 3);
            int sv = (int)seg[(z2 * 128 + y2) * 128 + x] & 255;
            if (sv == label)
                do_voxel_out(Bu, rr, x, z0, y0, out, kw);
            else if ((sv < 1 || sv > 8) && (((x & 7) + 1) == label))
                zero_voxel(rr, x, z0, y0, out);
        }
    }
}

__global__ __launch_bounds__(256) void seg_to_u8(const int* __restrict__ seg,
                                                 unsigned char* __restrict__ seg8) {
    const int t = blockIdx.x * 256 + threadIdx.x;          // 2048 blocks
    const int4 s = ((const int4*)seg)[t];
    ((uchar4*)seg8)[t] = make_uchar4((unsigned char)s.x, (unsigned char)s.y,
                                     (unsigned char)s.z, (unsigned char)s.w);
}

extern "C" void kernel_launch(void* const* d_in, const int* in_sizes, int n_in,
                              void* d_out, int out_size, void* d_ws, size_t ws_size,
                              hipStream_t stream) {
    const int* seg = (const int*)d_in[0];
    // d_in[1] (coords) unused: math is translation-invariant.
    float* out = (float*)d_out;
    unsigned short* A = (unsigned short*)d_ws;             // f16 A planes
    const size_t AVOL = (size_t)3 * NV;                    // u16 elements/label

    Kw kw;
    double gg[KL], S = 0.0;
    for (int j = 0; j < KL; ++j) { double d = j - R; gg[j] = exp(-0.5 * d * d / 25.0); S += gg[j]; }
    for (int j = 0; j < KL; ++j) {
        double gn = gg[j] / S, d = j - R;
        kw.k0[j] = (float)gn;
        kw.k1[j] = (float)(-d * gn);   // conv kernel k1 evaluated at (Z - t) = -d
        kw.k2[j] = (float)(d * d * gn);
    }

    // No memset: every output voxel is written exactly once across labels.

    const size_t need_all = 8 * AVOL * sizeof(unsigned short) + NV;  // A_all + seg8
    const size_t need_one = AVOL * sizeof(unsigned short) + NV;

    if (ws_size >= need_all) {
        // 3-dispatch path: labels batched in blockIdx.y, tile-major in x.
        unsigned char* seg8 = (unsigned char*)d_ws + 8 * AVOL * sizeof(unsigned short);
        seg_to_u8<<<dim3(2048), dim3(256), 0, stream>>>(seg, seg8);
        pass_z_t<unsigned char><<<dim3(512, 8), dim3(256), 0, stream>>>(
            seg8, A, 1, AVOL, kw);
        pass_yx<unsigned char><<<dim3(1024, 8), dim3(128), 0, stream>>>(
            A, seg8, out, 1, AVOL, kw);
    } else if (ws_size >= need_one) {
        unsigned char* seg8 = (unsigned char*)d_ws + AVOL * sizeof(unsigned short);
        seg_to_u8<<<dim3(2048), dim3(256), 0, stream>>>(seg, seg8);
        for (int label = 1; label <= 8; ++label) {
            pass_z_t<unsigned char><<<dim3(512, 1), dim3(256), 0, stream>>>(
                seg8, A, label, 0, kw);
            pass_yx<unsigned char><<<dim3(1024, 1), dim3(128), 0, stream>>>(
                A, seg8, out, label, 0, kw);
        }
    } else {
        for (int label = 1; label <= 8; ++label) {
            pass_z_t<int><<<dim3(512, 1), dim3(256), 0, stream>>>(
                seg, A, label, 0, kw);
            pass_yx<int><<<dim3(1024, 1), dim3(128), 0, stream>>>(
                A, seg, out, label, 0, kw);
        }
    }
}

// Round 12
// 420.393 us; speedup vs baseline: 1.5627x; 1.0058x over previous
//
#include <hip/hip_runtime.h>
#include <hip/hip_bf16.h>
#include <math.h>

// LSD (local shape descriptors), 128^3, 8 labels, sigma=5, truncate=3 -> 31-tap kernel.
//
// Algebra: for label mask m, define G_{abc} = (k_a *_z)(k_b *_y)(k_c *_x) m with
//   k0(u)=w(u), k1(u)=u w(u), k2(u)=u^2 w(u)  (w = normalized gaussian).
// At a voxel with mass=G000>0, p=G100/mass, q=G010/mass, s=G001/mass:
//   mean_offset = 0.5 - {p,q,s}/(2 sigma);  cov_ab = (G../mass - ..)/sigma^2.
// Translation-invariant: coords input not needed. Masks disjoint.
//
// Measured record (totals; pass_yx in parens):
//   R11 407 (289, bf16+kp, BEST pass_yx)  R12 452  R13 644  R14 488
//   R15 433 (313)  R16 409 (313)  R17 405 (302, f16+kq4)  R18 657 (spills)
//   R19 423 (302) -- LDS<=32KB "lever" was already true in R11 (LDS_Block
//   32768 there too); occupancy unchanged -> TLP refuted for pass_yx in its
//   cleanest form. pass_yx floor under this structure ~289-300.
// R20 (this round):
//   a) pass_yx: exact byte-level revert to R11 (bf16 A, kp[3][37] table,
//      LCAP 512) -- reclaim the best measured 289.
//   b) pass_z: x-pair threads. Old: 512 blk x 256 thr = 8 waves/CU, window
//      loop exposed at L2 latency (~200cyc vs ~120 issue-cyc/iter cover).
//      New: 1024 blk x 256 thr, thread = 4 z-outs x 2 x; same total load
//      bytes and FMAs, half VALU per thread, 16 waves/CU -> latency-hiding
//      doubled where there are no barriers/phases to correlate stalls.

constexpr int NV = 128 * 128 * 128;
constexpr int SLICE = 128 * 128;
constexpr int R = 15;
constexpr int KL = 31;
constexpr int CSTRIDE = 160;            // u16: 16 pad + 128 data + 16 pad
constexpr int RSTRIDE = 6 * CSTRIDE + 8; // 968 u16; row stagger: 242w = 18 mod 32
constexpr int LCAP = 512;

struct Kw { float k0[KL]; float k1[KL]; float k2[KL]; };

__device__ __forceinline__ void fma4(float4& a, float w, const float4& b) {
    a.x = fmaf(w, b.x, a.x); a.y = fmaf(w, b.y, a.y);
    a.z = fmaf(w, b.z, a.z); a.w = fmaf(w, b.w, a.w);
}
__device__ __forceinline__ void fma2(float2& a, float w, const float2& b) {
    a.x = fmaf(w, b.x, a.x); a.y = fmaf(w, b.y, a.y);
}

__device__ __forceinline__ float2 load_mask2(const unsigned char* p, int lab) {
    unsigned short u = *(const unsigned short*)p;
    return make_float2((u & 255u) == (unsigned)lab ? 1.f : 0.f,
                       (u >> 8)   == (unsigned)lab ? 1.f : 0.f);
}
__device__ __forceinline__ float2 load_mask2(const int* p, int lab) {
    int2 s = *(const int2*)p;
    return make_float2(s.x == lab ? 1.f : 0.f, s.y == lab ? 1.f : 0.f);
}

__device__ __forceinline__ unsigned seg_pack4(const unsigned char* p) {
    return *(const unsigned int*)p;
}
__device__ __forceinline__ unsigned seg_pack4(const int* p) {
    int4 v = *(const int4*)p;
    return (unsigned)(v.x & 255) | ((unsigned)(v.y & 255) << 8) |
           ((unsigned)(v.z & 255) << 16) | ((unsigned)(v.w & 255) << 24);
}

__device__ __forceinline__ float bf_ld(const unsigned short* p) {
    return __uint_as_float(((unsigned int)(*p)) << 16);
}

// 4 packed bf16 (as uint2) -> float4. 1 VALU op per value.
__device__ __forceinline__ float4 bf4_to_f4(uint2 u) {
    return make_float4(__uint_as_float(u.x << 16),
                       __uint_as_float(u.x & 0xFFFF0000u),
                       __uint_as_float(u.y << 16),
                       __uint_as_float(u.y & 0xFFFF0000u));
}

__device__ __forceinline__ unsigned pack_bf2(float a, float b) {
    __hip_bfloat162 h = __float22bfloat162_rn(make_float2(a, b));
    return *reinterpret_cast<unsigned*>(&h);
}

// -------- pass_z: seg -> A[lab][3] bf16 (z-conv). grid (1024, nlab), 256 thr.
// x-pair threads: thread = 4 z-outs x 2 x. 16 waves/CU (was 8); same total
// load bytes/FMAs as the 4-x version; 2-deep pipelined window.
template <typename ST>
__global__ __launch_bounds__(256) void pass_z_t(const ST* __restrict__ seg,
                                                unsigned short* __restrict__ A,
                                                int label0, size_t a_stride,
                                                Kw kw) {
    __shared__ float kp[3][37];           // zero-padded: kp[c][i] = k_c[i-3]
    if (threadIdx.x < 37) {
        int i = threadIdx.x, j = i - 3; bool ok = (j >= 0) && (j < KL);
        kp[0][i] = ok ? kw.k0[j] : 0.f;
        kp[1][i] = ok ? kw.k1[j] : 0.f;
        kp[2][i] = ok ? kw.k2[j] : 0.f;
    }
    __syncthreads();
    const int label = label0 + blockIdx.y;
    unsigned short* Ab = A + (size_t)blockIdx.y * a_stride;
    const int h = blockIdx.x, g = h & 7, l = h >> 3;       // 1024 blocks
    const int tx = threadIdx.x & 63, ty = threadIdx.x >> 6; // 64 x-pairs, 4 y
    const int x0 = tx * 2;
    const int z0 = 16 * g + 4 * (l & 3);                   // XCD g owns z [16g,16g+16)
    const int y  = (l >> 2) * 4 + ty;                      // 32 y-groups of 4

    float2 acc[4][3];
#pragma unroll
    for (int t = 0; t < 4; ++t)
#pragma unroll
        for (int c = 0; c < 3; ++c) acc[t][c] = make_float2(0.f, 0.f);

    // 2-deep pipelined sliding window: load j+2 while FMAing j.
    float2 cm = make_float2(0.f, 0.f), nm = cm;
    {
        int zz = z0 - R;
        if ((unsigned)zz < 128u)
            cm = load_mask2(seg + (zz * SLICE + y * 128 + x0), label);
        int zn = z0 + 1 - R;
        if ((unsigned)zn < 128u)
            nm = load_mask2(seg + (zn * SLICE + y * 128 + x0), label);
    }
    for (int j = 0; j < 34; ++j) {                         // window: 4 outs + 30
        float2 fm = make_float2(0.f, 0.f);
        int zz = z0 + j + 2 - R;                           // uniform per wave
        if (j < 32 && (unsigned)zz < 128u)
            fm = load_mask2(seg + (zz * SLICE + y * 128 + x0), label);
#pragma unroll
        for (int t = 0; t < 4; ++t) {
            int i = j - t + 3;                             // padded weight index
            fma2(acc[t][0], kp[0][i], cm);
            fma2(acc[t][1], kp[1][i], cm);
            fma2(acc[t][2], kp[2][i], cm);
        }
        cm = nm; nm = fm;
    }
#pragma unroll
    for (int t = 0; t < 4; ++t) {
        int base = (z0 + t) * SLICE + y * 128 + x0;
#pragma unroll
        for (int c = 0; c < 3; ++c)
            *reinterpret_cast<unsigned*>(Ab + (size_t)c * NV + base) =
                pack_bf2(acc[t][c].x, acc[t][c].y);
    }
}

// ---- per-voxel sparse x-conv + epilogue (B rows in bf16 LDS, zero-padded) -
__device__ __forceinline__ void conv_voxel(const unsigned short* __restrict__ Bu,
                                           int rr, int x, const Kw& kw,
                                           float o[10]) {
    const unsigned short* row = Bu + rr * RSTRIDE + (x + 1);
    float g000 = 0, g001 = 0, g002 = 0, g010 = 0, g011 = 0,
          g020 = 0, g100 = 0, g101 = 0, g110 = 0, g200 = 0;
#pragma unroll
    for (int j = 0; j < KL; ++j) {
        float w0 = kw.k0[j], w1 = kw.k1[j], w2 = kw.k2[j];
        float b0 = bf_ld(row + 0 * CSTRIDE + j);
        float b1 = bf_ld(row + 1 * CSTRIDE + j);
        float b2 = bf_ld(row + 2 * CSTRIDE + j);
        float b3 = bf_ld(row + 3 * CSTRIDE + j);
        float b4 = bf_ld(row + 4 * CSTRIDE + j);
        float b5 = bf_ld(row + 5 * CSTRIDE + j);
        g000 = fmaf(w0, b0, g000); g001 = fmaf(w1, b0, g001); g002 = fmaf(w2, b0, g002);
        g010 = fmaf(w0, b1, g010); g011 = fmaf(w1, b1, g011);
        g020 = fmaf(w0, b2, g020);
        g100 = fmaf(w0, b3, g100); g101 = fmaf(w1, b3, g101);
        g110 = fmaf(w0, b4, g110);
        g200 = fmaf(w0, b5, g200);
    }
    float mass = g000;
    float denom = (mass > 0.f) ? mass : 1.f;
    float inv = 1.f / denom;
    float p = g100 * inv, q = g010 * inv, s = g001 * inv;
    const float cs = 1.0f / 25.0f;                         // 1/sigma^2
    o[0] = 0.5f - 0.1f * p;                                // 1/(2 sigma) = 0.1
    o[1] = 0.5f - 0.1f * q;
    o[2] = 0.5f - 0.1f * s;
    o[3] = (g200 * inv - p * p) * cs;
    o[4] = (g020 * inv - q * q) * cs;
    o[5] = (g002 * inv - s * s) * cs;
    o[6] = (g110 * inv - p * q) * cs;
    o[7] = (g011 * inv - q * s) * cs;
    o[8] = (g101 * inv - p * s) * cs;
    o[9] = mass;
#pragma unroll
    for (int c = 0; c < 10; ++c) o[c] = fminf(fmaxf(o[c], 0.f), 1.f);
}

__device__ __forceinline__ void do_voxel_out(const unsigned short* __restrict__ Bu,
                                             int rr, int x, int z0, int y0,
                                             float* __restrict__ out, const Kw& kw) {
    float o[10];
    conv_voxel(Bu, rr, x, kw, o);
    const int z2 = z0 + (rr >> 2), y2 = y0 + (rr & 3);
    const int v = (z2 * 128 + y2) * 128 + x;
#pragma unroll
    for (int c = 0; c < 10; ++c) out[(size_t)c * NV + v] = o[c];
}

__device__ __forceinline__ void zero_voxel(int rr, int x, int z0, int y0,
                                           float* __restrict__ out) {
    const int z2 = z0 + (rr >> 2), y2 = y0 + (rr & 3);
    const int v = (z2 * 128 + y2) * 128 + x;
#pragma unroll
    for (int c = 0; c < 10; ++c) out[(size_t)c * NV + v] = 0.f;
}

// -------- pass_yx: A[lab][3] bf16 -> out. grid (1024, nlab), 128 thr. ------
// EXACT R11 structure (best measured: 289 us): 16-row tile (4z x 4y), T=4
// sliding y-outs, 2-deep pipeline, kp[3][37] f32 weight table, planar bf16
// Bu, register-pk ballot compaction, direct f32 stores, zero-designation
// full coverage (no memset).
template <typename ST>
__global__ __launch_bounds__(128) void pass_yx(const unsigned short* __restrict__ A,
                                               const ST* __restrict__ seg,
                                               float* __restrict__ out,
                                               int label0, size_t a_stride,
                                               Kw kw) {
    __shared__ float kp[3][37];
    __shared__ __align__(16) unsigned short Bu[16 * RSTRIDE]; // 30,976 B
    __shared__ unsigned short lst[LCAP];                      // 1 KB
    __shared__ int cnt;

    // zero Bu (pads must be exactly 0) + weights + counter
    {
        uint4 z4 = make_uint4(0, 0, 0, 0);
        uint4* b4 = (uint4*)Bu;                            // 16*968/8 = 1936
        for (int i = threadIdx.x; i < 1936; i += 128) b4[i] = z4;
    }
    if (threadIdx.x < 37) {
        int i = threadIdx.x, j = i - 3; bool ok = (j >= 0) && (j < KL);
        kp[0][i] = ok ? kw.k0[j] : 0.f;
        kp[1][i] = ok ? kw.k1[j] : 0.f;
        kp[2][i] = ok ? kw.k2[j] : 0.f;
    }
    if (threadIdx.x == 0) cnt = 0;
    __syncthreads();

    const int labi = blockIdx.y;
    const int label = label0 + labi;
    const unsigned short* Ab = A + (size_t)labi * a_stride;
    const int h = blockIdx.x, g = h & 7, l = h >> 3;       // 1024 x-blocks
    const int tx = threadIdx.x & 31, tz = threadIdx.x >> 5; // tz 0..3
    const int x0 = tx * 4;
    const int z0 = 16 * g + 4 * (l & 3);                   // XCD g owns z slab
    const int y0 = (l >> 2) * 4;                           // 32 y-tiles
    const int zs = (z0 + tz) * SLICE;

    // pre-issue compaction seg loads (complete under phase 1)
    const int rr_c = threadIdx.x >> 3, q0_c = threadIdx.x & 7;
    const int vrow_c = ((z0 + (rr_c >> 2)) * 128 + (y0 + (rr_c & 3))) * 128;
    unsigned pk[4];
#pragma unroll
    for (int k = 0; k < 4; ++k)
        pk[k] = seg_pack4(seg + vrow_c + 4 * (q0_c + 8 * k));

    // ---- phase 1: y-conv, T=4 outputs sliding in registers, 2-deep pipe ----
    float4 acc[6][4];                                      // [ch][t]
#pragma unroll
    for (int c = 0; c < 6; ++c)
#pragma unroll
        for (int t = 0; t < 4; ++t) acc[c][t] = make_float4(0.f, 0.f, 0.f, 0.f);

    uint2 c0 = make_uint2(0u, 0u), c1 = c0, c2 = c0;       // packed bf16 x4
    uint2 n0 = c0, n1 = c0, n2 = c0;
    {
        int yy = y0 - R;
        if ((unsigned)yy < 128u) {
            int base = zs + yy * 128 + x0;
            c0 = *(const uint2*)(Ab + base);
            c1 = *(const uint2*)(Ab + NV + base);
            c2 = *(const uint2*)(Ab + 2 * NV + base);
        }
        int yn = y0 + 1 - R;
        if ((unsigned)yn < 128u) {
            int base = zs + yn * 128 + x0;
            n0 = *(const uint2*)(Ab + base);
            n1 = *(const uint2*)(Ab + NV + base);
            n2 = *(const uint2*)(Ab + 2 * NV + base);
        }
    }
    for (int j = 0; j < 34; ++j) {
        uint2 f0 = make_uint2(0u, 0u), f1 = f0, f2 = f0;
        int yy = y0 + j + 2 - R;
        if (j < 32 && (unsigned)yy < 128u) {
            int base = zs + yy * 128 + x0;
            f0 = *(const uint2*)(Ab + base);
            f1 = *(const uint2*)(Ab + NV + base);
            f2 = *(const uint2*)(Ab + 2 * NV + base);
        }
        float4 a0 = bf4_to_f4(c0), a1 = bf4_to_f4(c1), a2 = bf4_to_f4(c2);
#pragma unroll
        for (int t = 0; t < 4; ++t) {
            int i = j - t + 3;
            float w0 = kp[0][i], w1 = kp[1][i], w2 = kp[2][i];
            fma4(acc[0][t], w0, a0);
            fma4(acc[1][t], w1, a0);
            fma4(acc[2][t], w2, a0);
            fma4(acc[3][t], w0, a1);
            fma4(acc[4][t], w1, a1);
            fma4(acc[5][t], w0, a2);
        }
        c0 = n0; c1 = n1; c2 = n2;
        n0 = f0; n1 = f1; n2 = f2;
    }
#pragma unroll
    for (int t = 0; t < 4; ++t) {
        const int row = tz * 4 + t;                        // row = 4*zsub + ysub
#pragma unroll
        for (int c = 0; c < 6; ++c) {
            uint2 pv = make_uint2(pack_bf2(acc[c][t].x, acc[c][t].y),
                                  pack_bf2(acc[c][t].z, acc[c][t].w));
            *reinterpret_cast<uint2*>(Bu + row * RSTRIDE + c * CSTRIDE + 16 + x0) = pv;
        }
    }

    // ---- compaction: ballot-based, 1 atomic per wave per step ----
    {
        const int lane = threadIdx.x & 63;
        const unsigned long long below_mask = (1ull << lane) - 1ull;
#pragma unroll
        for (int k = 0; k < 4; ++k) {
            const unsigned w = pk[k];
#pragma unroll
            for (int t = 0; t < 4; ++t) {
                const int sv = (int)((w >> (8 * t)) & 255u);
                const int x = 4 * (q0_c + 8 * k) + t;
                const bool mt = (sv == label);
                const bool zt = !mt && (sv < 1 || sv > 8) &&
                                (((x & 7) + 1) == label);
                const bool pred = mt | zt;
                unsigned long long bal = __ballot(pred);
                int base = 0;
                if (lane == 0 && bal) base = atomicAdd(&cnt, (int)__popcll(bal));
                base = __shfl(base, 0);
                if (pred) {
                    int pos = base + (int)__popcll(bal & below_mask);
                    if (pos < LCAP)
                        lst[pos] = (unsigned short)((rr_c << 7) | x | (zt ? 0x8000 : 0));
                }
            }
        }
    }

    __syncthreads();

    // ---- phase 2: sparse x-conv + epilogue (or zero-store) ----
    const int total = cnt;
    if (total <= LCAP) {
        for (int e = threadIdx.x; e < total; e += 128) {
            int ent = lst[e];
            int rr = (ent >> 7) & 15, x = ent & 127;
            if (ent & 0x8000) zero_voxel(rr, x, z0, y0, out);
            else do_voxel_out(Bu, rr, x, z0, y0, out, kw);
        }
    } else {
        // adversarial-density fallback: dense masked sweep (same math)
        for (int e = threadIdx.x; e < 2048; e += 128) {
            int rr = e >> 7, x = e & 127;
            int z2 = z0 + (rr >> 2), y2 = y0 + (rr & 3);
            int sv = (int)seg[(z2 * 128 + y2) * 128 + x] & 255;
            if (sv == label)
                do_voxel_out(Bu, rr, x, z0, y0, out, kw);
            else if ((sv < 1 || sv > 8) && (((x & 7) + 1) == label))
                zero_voxel(rr, x, z0, y0, out);
        }
    }
}

__global__ __launch_bounds__(256) void seg_to_u8(const int* __restrict__ seg,
                                                 unsigned char* __restrict__ seg8) {
    const int t = blockIdx.x * 256 + threadIdx.x;          // 2048 blocks
    const int4 s = ((const int4*)seg)[t];
    ((uchar4*)seg8)[t] = make_uchar4((unsigned char)s.x, (unsigned char)s.y,
                                     (unsigned char)s.z, (unsigned char)s.w);
}

extern "C" void kernel_launch(void* const* d_in, const int* in_sizes, int n_in,
                              void* d_out, int out_size, void* d_ws, size_t ws_size,
                              hipStream_t stream) {
    const int* seg = (const int*)d_in[0];
    // d_in[1] (coords) unused: math is translation-invariant.
    float* out = (float*)d_out;
    unsigned short* A = (unsigned short*)d_ws;             // bf16 A planes
    const size_t AVOL = (size_t)3 * NV;                    // u16 elements/label

    Kw kw;
    double gg[KL], S = 0.0;
    for (int j = 0; j < KL; ++j) { double d = j - R; gg[j] = exp(-0.5 * d * d / 25.0); S += gg[j]; }
    for (int j = 0; j < KL; ++j) {
        double gn = gg[j] / S, d = j - R;
        kw.k0[j] = (float)gn;
        kw.k1[j] = (float)(-d * gn);   // conv kernel k1 evaluated at (Z - t) = -d
        kw.k2[j] = (float)(d * d * gn);
    }

    // No memset: every output voxel is written exactly once across labels.

    const size_t need_all = 8 * AVOL * sizeof(unsigned short) + NV;  // A_all + seg8
    const size_t need_one = AVOL * sizeof(unsigned short) + NV;

    if (ws_size >= need_all) {
        // 3-dispatch path: labels batched in blockIdx.y, tile-major in x.
        unsigned char* seg8 = (unsigned char*)d_ws + 8 * AVOL * sizeof(unsigned short);
        seg_to_u8<<<dim3(2048), dim3(256), 0, stream>>>(seg, seg8);
        pass_z_t<unsigned char><<<dim3(1024, 8), dim3(256), 0, stream>>>(
            seg8, A, 1, AVOL, kw);
        pass_yx<unsigned char><<<dim3(1024, 8), dim3(128), 0, stream>>>(
            A, seg8, out, 1, AVOL, kw);
    } else if (ws_size >= need_one) {
        unsigned char* seg8 = (unsigned char*)d_ws + AVOL * sizeof(unsigned short);
        seg_to_u8<<<dim3(2048), dim3(256), 0, stream>>>(seg, seg8);
        for (int label = 1; label <= 8; ++label) {
            pass_z_t<unsigned char><<<dim3(1024, 1), dim3(256), 0, stream>>>(
                seg8, A, label, 0, kw);
            pass_yx<unsigned char><<<dim3(1024, 1), dim3(128), 0, stream>>>(
                A, seg8, out, label, 0, kw);
        }
    } else {
        for (int label = 1; label <= 8; ++label) {
            pass_z_t<int><<<dim3(1024, 1), dim3(256), 0, stream>>>(
                seg, A, label, 0, kw);
            pass_yx<int><<<dim3(1024, 1), dim3(128), 0, stream>>>(
                A, seg, out, label, 0, kw);
        }
    }
}